// Round 9
// baseline (651.280 us; speedup 1.0000x reference)
//
#include <hip/hip_runtime.h>
#include <math.h>

#define N_NODES 50000
#define N_EDGES 600000
#define N_GRAPHS 512
#define HID 128
#define LAT 64
#define NL 4
#define SSTR 16        // stats padding: 1 float per 64B cache line
#define NGRP 16        // stat/barrier groups
#define PSET (NGRP * 256 * SSTR)  // floats per partial stat set: 65536
#define N_TILES 3125   // 16-row tiles, exact
#define ZROWS 208      // max rows per persistent block: ceil(3125/256)*16
#define ZLD 136        // LDS z-tile row stride in ushorts (128 + 8 pad)

typedef __attribute__((ext_vector_type(8))) __bf16 bf16x8;
typedef __attribute__((ext_vector_type(4))) float f32x4;

union Chunk {
    bf16x8 v;
    uint4 u4;
    ushort us[8];
};

__device__ __forceinline__ float gelu_exact(float x) {
    return 0.5f * x * (1.0f + erff(x * 0.70710678118654752f));
}
// Branchless gelu via A&S 7.1.26 erf poly (|err| <= 1.5e-7) + fast exp/rcp.
__device__ __forceinline__ float gelu_fast(float x) {
    float ax = fabsf(x) * 0.70710678118654752f;
    float t = __builtin_amdgcn_rcpf(fmaf(0.3275911f, ax, 1.0f));
    float p = t * (0.254829592f +
              t * (-0.284496736f +
              t * (1.421413741f +
              t * (-1.453152027f + t * 1.061405429f))));
    float e = __expf(-ax * ax);
    float erfv = 1.0f - p * e;
    float erfs = copysignf(erfv, x);
    return 0.5f * x * (1.0f + erfs);
}
__device__ __forceinline__ float bf2f(ushort h) {
    return __uint_as_float(((unsigned int)h) << 16);
}
__device__ __forceinline__ ushort f2bf(float f) {  // RNE
    unsigned int u = __float_as_uint(f);
    unsigned int r = (u + 0x7FFFu + ((u >> 16) & 1u)) >> 16;
    return (ushort)r;
}
// float atomic max via sign trick (init to -inf)
__device__ __forceinline__ void atomicMaxF(float* addr, float v) {
    if (v >= 0.f) atomicMax((int*)addr, __float_as_int(v));
    else atomicMin((unsigned int*)addr, __float_as_uint(v));
}

// Canonical row partition p (0..255) -> sub-chunk j (0..7) -> [s0, s1)
__device__ __forceinline__ void sub_range(int p, int j, int& s0, int& s1) {
    int r0 = (p * N_NODES) >> 8;
    int r1 = ((p + 1) * N_NODES) >> 8;
    int len = r1 - r0;
    s0 = r0 + ((len * j) >> 3);
    s1 = r0 + ((len * (j + 1)) >> 3);
}

// Grouped fence-free grid barrier (mechanism cost ~1.2-2.3us/barrier, r6).
// Region layout (ints): [64+g*16] group counters, [320] master, [336] flag.
__device__ __forceinline__ void grid_sync(int* bar, int epoch) {
    __syncthreads();
    if (threadIdx.x == 0) {
        int g = blockIdx.x & (NGRP - 1);
        int prev = __hip_atomic_fetch_add(bar + 64 + g * 16, 1, __ATOMIC_RELAXED,
                                          __HIP_MEMORY_SCOPE_AGENT);
        if (prev == NGRP * epoch - 1) {  // last of my group this epoch
            int mp = __hip_atomic_fetch_add(bar + 320, 1, __ATOMIC_RELAXED,
                                            __HIP_MEMORY_SCOPE_AGENT);
            if (mp == NGRP * epoch - 1)  // last group overall
                __hip_atomic_store(bar + 336, epoch, __ATOMIC_RELAXED,
                                   __HIP_MEMORY_SCOPE_AGENT);
        }
        while (__hip_atomic_load(bar + 336, __ATOMIC_RELAXED,
                                 __HIP_MEMORY_SCOPE_AGENT) < epoch)
            __builtin_amdgcn_s_sleep(4);
    }
    __syncthreads();
    asm volatile("" ::: "memory");  // pin compiler ordering of post-barrier loads
}

// coherent (agent-scope) float load, bypasses incoherent L1/L2
__device__ __forceinline__ float coh_ld(const float* p) {
    return __hip_atomic_load((const float*)p, __ATOMIC_RELAXED, __HIP_MEMORY_SCOPE_AGENT);
}

// ---------------------------------------------------------------------------
// Fused setup: weight pre-transpose + zero counts/partial-stats + pool/
// barrier init. Grid 512x256.
// ---------------------------------------------------------------------------
__global__ __launch_bounds__(256) void setup(const float* __restrict__ fc1w,
                                             const float* __restrict__ fc2w,
                                             ushort* __restrict__ Wt,
                                             int* __restrict__ counts,
                                             float* __restrict__ statsPart,
                                             float* __restrict__ psum,
                                             float* __restrict__ pmax,
                                             int* __restrict__ gstart,
                                             int* __restrict__ gend,
                                             int* __restrict__ bar) {
    int i = blockIdx.x * 256 + threadIdx.x;  // always < 131072 == 8*HID*HID
    {
        int g = i >> 14;
        int rem = i & 16383;
        int n = rem >> 7, k = rem & 127;
        const float* W = (g < 4) ? (fc1w + (long)g * HID * HID)
                                 : (fc2w + (long)(g - 4) * HID * HID);
        Wt[i] = f2bf(W[k * HID + n]);
    }
    if (i < N_NODES) counts[i] = 0;
    for (long j = i; j < (long)9 * PSET; j += 131072) statsPart[j] = 0.f;
    if (i < N_GRAPHS * HID) { psum[i] = 0.f; pmax[i] = -INFINITY; }
    if (i < N_GRAPHS) { gstart[i] = 0; gend[i] = 0; }
    if (i < 2048) bar[i] = 0;
}

// ---------------------------------------------------------------------------
// Fused: col stats over fp32 X (blocks 0..255, grouped partial writes) +
// CSR degree count (256..2599) + graph ranges (2600..2795). Grid 2796.
// ---------------------------------------------------------------------------
__global__ __launch_bounds__(256) void stats_count(const float* __restrict__ X,
                                                   float* __restrict__ inPart,
                                                   const int* __restrict__ dst,
                                                   int* __restrict__ counts,
                                                   const int* __restrict__ batch,
                                                   int* __restrict__ gstart,
                                                   int* __restrict__ gend) {
    __shared__ float sh[2048];
    int bx = blockIdx.x;
    int t = threadIdx.x;
    if (bx < 256) {
        int tx = t & 31, ty = t >> 5;
        float s[4] = {0, 0, 0, 0}, q[4] = {0, 0, 0, 0};
        const int nTiles = (N_NODES + 63) / 64;  // 782
        for (int tile = bx; tile < nTiles; tile += 256) {
            int r0 = tile * 64;
#pragma unroll
            for (int i = 0; i < 8; ++i) {
                int r = r0 + ty + 8 * i;
                int rc = min(r, N_NODES - 1);
                float4 v = *(const float4*)(X + (long)rc * HID + 4 * tx);
                float w = (r < N_NODES) ? 1.f : 0.f;
                float x0 = v.x * w, x1 = v.y * w, x2 = v.z * w, x3 = v.w * w;
                s[0] += x0; s[1] += x1; s[2] += x2; s[3] += x3;
                q[0] += x0 * v.x; q[1] += x1 * v.y; q[2] += x2 * v.z; q[3] += x3 * v.w;
            }
        }
#pragma unroll
        for (int c = 0; c < 4; ++c) {
            sh[ty * HID + 4 * tx + c] = s[c];
            sh[1024 + ty * HID + 4 * tx + c] = q[c];
        }
        __syncthreads();
        if (ty == 0) {
            int grp = bx & (NGRP - 1);
            float* base = inPart + (long)(grp * 256) * SSTR;
#pragma unroll
            for (int c = 0; c < 4; ++c) {
                float a = 0, b = 0;
#pragma unroll
                for (int j = 0; j < 8; ++j) {
                    a += sh[j * HID + 4 * tx + c];
                    b += sh[1024 + j * HID + 4 * tx + c];
                }
                atomicAdd(base + (4 * tx + c) * SSTR, a);
                atomicAdd(base + (HID + 4 * tx + c) * SSTR, b);
            }
        }
    } else if (bx < 2600) {
        int e = (bx - 256) * 256 + t;
        if (e < N_EDGES) atomicAdd(counts + dst[e], 1);
    } else {
        int n = (bx - 2600) * 256 + t;
        if (n < N_NODES) {
            int b = batch[n];
            if (n == 0 || batch[n - 1] != b) gstart[b] = n;
            if (n == N_NODES - 1 || batch[n + 1] != b) gend[b] = n + 1;
        }
    }
}

// ---------------------------------------------------------------------------
// Fused: input-BN apply fp32->bf16 + scan pass 1 over counts (blocks 0..195).
// ---------------------------------------------------------------------------
__global__ __launch_bounds__(256) void bn_scan(const float* __restrict__ X,
                                               ushort* __restrict__ Y,
                                               const float* __restrict__ inPart,
                                               const float* __restrict__ g,
                                               const float* __restrict__ b,
                                               const int* __restrict__ counts,
                                               int* __restrict__ offs,
                                               int* __restrict__ bsum) {
    __shared__ float scL[HID], sfL[HID];
    __shared__ int shI[256];
    int t = threadIdx.x;
    if (t < HID) {
        float sm = 0.f, sq = 0.f;
#pragma unroll
        for (int gg = 0; gg < NGRP; ++gg) {
            sm += inPart[((long)gg * 256 + t) * SSTR];
            sq += inPart[((long)gg * 256 + HID + t) * SSTR];
        }
        const float invN = 1.0f / (float)N_NODES;
        float mean = sm * invN;
        float var = sq * invN - mean * mean;
        float s = g[t] * rsqrtf(var + 1e-5f);
        scL[t] = s;
        sfL[t] = b[t] - mean * s;
    }
    __syncthreads();
    int c4 = (t & 31) * 4;
    float sc[4], sf[4];
#pragma unroll
    for (int j = 0; j < 4; ++j) { sc[j] = scL[c4 + j]; sf[j] = sfL[c4 + j]; }
    int s0, s1;
    sub_range(blockIdx.x & 255, blockIdx.x >> 8, s0, s1);
    int c0 = s0 * 32, c1 = s1 * 32;
    for (int i = c0 + t; i < c1; i += 256) {
        float4 v = ((const float4*)X)[i];
        ushort4 w;
        w.x = f2bf(v.x * sc[0] + sf[0]);
        w.y = f2bf(v.y * sc[1] + sf[1]);
        w.z = f2bf(v.z * sc[2] + sf[2]);
        w.w = f2bf(v.w * sc[3] + sf[3]);
        ((ushort4*)Y)[i] = w;
    }
    // scan pass 1 (block-local exclusive scan + block totals)
    if (blockIdx.x < 196) {
        int i = blockIdx.x * 256 + t;
        int v = (i < N_NODES) ? counts[i] : 0;
        shI[t] = v;
        __syncthreads();
        for (int off = 1; off < 256; off <<= 1) {
            int a = (t >= off) ? shI[t - off] : 0;
            __syncthreads();
            shI[t] += a;
            __syncthreads();
        }
        if (i < N_NODES) offs[i] = shI[t] - v;
        if (t == 255) bsum[blockIdx.x] = shI[255];
    }
}

// ---------------------------------------------------------------------------
// Scan passes 2+3 fused. Writes offs + cursor.
// ---------------------------------------------------------------------------
__global__ __launch_bounds__(256) void scan23(int* __restrict__ offs,
                                              const int* __restrict__ bsum,
                                              int* __restrict__ cursor) {
    __shared__ int sh[256];
    int t = threadIdx.x, bx = blockIdx.x;
    int v = (t < bx) ? bsum[t] : 0;
    sh[t] = v;
    __syncthreads();
    for (int off = 128; off > 0; off >>= 1) {
        if (t < off) sh[t] += sh[t + off];
        __syncthreads();
    }
    int pre = sh[0];
    int i = bx * 256 + t;
    if (i < N_NODES) {
        int o = offs[i] + pre;
        offs[i] = o;
        cursor[i] = o;
    }
}

__global__ __launch_bounds__(256) void csr_fill(const int* __restrict__ src,
                                                const int* __restrict__ dst,
                                                int* __restrict__ cursor,
                                                int* __restrict__ csr) {
    int e = blockIdx.x * blockDim.x + threadIdx.x;
    if (e >= N_EDGES) return;
    int pos = atomicAdd(cursor + dst[e], 1);
    csr[pos] = src[e];
}

// ---------------------------------------------------------------------------
// Dedicated GIN aggregation (fusing it into the persistent kernel LOST r7:
// 8 waves/CU is latency-starved for streaming work). Grid 2048.
// ---------------------------------------------------------------------------
__global__ __launch_bounds__(256) void gin_gather_bf(const ushort* __restrict__ Xbf,
                                                     ushort* __restrict__ Hp,
                                                     const int* __restrict__ offs,
                                                     const int* __restrict__ counts,
                                                     const int* __restrict__ csr,
                                                     const float* __restrict__ eps, int l) {
    int t = threadIdx.x;
    int tx = t & 31;
    int grp = t >> 5;
    int s0, s1;
    sub_range(blockIdx.x & 255, blockIdx.x >> 8, s0, s1);
    float ev = 1.0f + eps[l];
    for (int node = s0 + grp; node < s1; node += 8) {
        ushort4 sv = *(const ushort4*)(Xbf + (long)node * HID + 4 * tx);
        float a0 = bf2f(sv.x) * ev, a1 = bf2f(sv.y) * ev;
        float a2 = bf2f(sv.z) * ev, a3 = bf2f(sv.w) * ev;
        int o = offs[node];
        int d = counts[node];
        int k = 0;
        for (; k + 8 <= d; k += 8) {
            int si[8];
#pragma unroll
            for (int j = 0; j < 8; ++j) si[j] = csr[o + k + j];
            ushort4 v[8];
#pragma unroll
            for (int j = 0; j < 8; ++j)
                v[j] = *(const ushort4*)(Xbf + (long)si[j] * HID + 4 * tx);
#pragma unroll
            for (int j = 0; j < 8; ++j) {
                a0 += bf2f(v[j].x); a1 += bf2f(v[j].y);
                a2 += bf2f(v[j].z); a3 += bf2f(v[j].w);
            }
        }
        for (; k + 4 <= d; k += 4) {
            int si[4];
#pragma unroll
            for (int j = 0; j < 4; ++j) si[j] = csr[o + k + j];
#pragma unroll
            for (int j = 0; j < 4; ++j) {
                ushort4 v = *(const ushort4*)(Xbf + (long)si[j] * HID + 4 * tx);
                a0 += bf2f(v.x); a1 += bf2f(v.y); a2 += bf2f(v.z); a3 += bf2f(v.w);
            }
        }
        for (; k < d; ++k) {
            int s = csr[o + k];
            ushort4 v = *(const ushort4*)(Xbf + (long)s * HID + 4 * tx);
            a0 += bf2f(v.x); a1 += bf2f(v.y); a2 += bf2f(v.z); a3 += bf2f(v.w);
        }
        ushort4 w;
        w.x = f2bf(a0); w.y = f2bf(a1); w.z = f2bf(a2); w.w = f2bf(a3);
        *(ushort4*)(Hp + (long)node * HID + 4 * tx) = w;
    }
}

// ---------------------------------------------------------------------------
// NON-PERSISTENT GEMM (arm P): grid 3125, one 16-row tile per block, 4 waves
// (wave w owns 32 output cols). ~16-20 waves/CU occupancy; no grid barrier —
// stats flow through grouped partials + kernel boundary. Optional fused
// BN+gelu on A-load (applyIn). Tests the "persistent kernel is latency-
// starved" hypothesis (r7/r8: dedicated high-occupancy kernels beat 8-wave
// persistent fusion twice).
// ---------------------------------------------------------------------------
__global__ __launch_bounds__(256) void gemm_np(
    const ushort* __restrict__ Abf, const ushort* __restrict__ Wt,
    const float* __restrict__ bias, ushort* __restrict__ Cbf,
    const float* __restrict__ stInPart, const float* __restrict__ gIn,
    const float* __restrict__ bIn, int applyIn, float* __restrict__ stOutPart) {
    __shared__ float scL[HID], sfL[HID];
    __shared__ __align__(16) ushort T[16 * ZLD];
    __shared__ float shs[2 * HID];
    int t = threadIdx.x;
    if (applyIn && t < HID) {
        float sm = 0.f, sq = 0.f;
#pragma unroll
        for (int gg = 0; gg < NGRP; ++gg) {
            sm += stInPart[((long)gg * 256 + t) * SSTR];
            sq += stInPart[((long)gg * 256 + HID + t) * SSTR];
        }
        const float invN = 1.0f / (float)N_NODES;
        float mean = sm * invN;
        float var = sq * invN - mean * mean;
        float s = gIn[t] * rsqrtf(var + 1e-5f);
        scL[t] = s;
        sfL[t] = bIn[t] - mean * s;
    }
    __syncthreads();

    int w = t >> 6, lane = t & 63;
    int m = lane & 15, q = lane >> 4;
    int tile = blockIdx.x;

    // A tile: 16 rows x 128 cols; each lane holds row m, cols q*8 + kc*32
    Chunk Ac[4];
    {
        const ushort* ar = Abf + (long)(tile * 16 + m) * HID + q * 8;
#pragma unroll
        for (int kc = 0; kc < 4; ++kc) Ac[kc].u4 = *(const uint4*)(ar + kc * 32);
    }
    if (applyIn) {
#pragma unroll
        for (int kc = 0; kc < 4; ++kc)
#pragma unroll
            for (int j = 0; j < 8; ++j) {
                int k = kc * 32 + q * 8 + j;
                float f = bf2f(Ac[kc].us[j]) * scL[k] + sfL[k];
                Ac[kc].us[j] = f2bf(gelu_fast(f));
            }
    }
    // B fragments: wave w covers cols [w*32, w*32+32)
    bf16x8 Bf[2][4];
    {
        const ushort* Wh = Wt + (long)(w * 32) * HID;
#pragma unroll
        for (int nt = 0; nt < 2; ++nt)
#pragma unroll
            for (int kc = 0; kc < 4; ++kc)
                Bf[nt][kc] = *(const bf16x8*)(Wh + (nt * 16 + m) * HID + kc * 32 + q * 8);
    }
    float bias2[2] = {bias[w * 32 + m], bias[w * 32 + 16 + m]};

    f32x4 acc[2];
#pragma unroll
    for (int nt = 0; nt < 2; ++nt) acc[nt] = (f32x4){0.f, 0.f, 0.f, 0.f};
#pragma unroll
    for (int kc = 0; kc < 4; ++kc)
#pragma unroll
        for (int nt = 0; nt < 2; ++nt)
            acc[nt] = __builtin_amdgcn_mfma_f32_16x16x32_bf16(Ac[kc].v, Bf[nt][kc],
                                                              acc[nt], 0, 0, 0);
    float s_c[2] = {0.f, 0.f}, q_c[2] = {0.f, 0.f};
#pragma unroll
    for (int nt = 0; nt < 2; ++nt) {
        int col = w * 32 + nt * 16 + m;
#pragma unroll
        for (int r = 0; r < 4; ++r) {
            float z = acc[nt][r] + bias2[nt];
            T[(q * 4 + r) * ZLD + col] = f2bf(z);
            s_c[nt] += z;
            q_c[nt] += z * z;
        }
    }
#pragma unroll
    for (int nt = 0; nt < 2; ++nt) {
        s_c[nt] += __shfl_xor(s_c[nt], 16);
        s_c[nt] += __shfl_xor(s_c[nt], 32);
        q_c[nt] += __shfl_xor(q_c[nt], 16);
        q_c[nt] += __shfl_xor(q_c[nt], 32);
    }
    if (q == 0) {
#pragma unroll
        for (int nt = 0; nt < 2; ++nt) {
            int col = w * 32 + nt * 16 + m;
            shs[col] = s_c[nt];
            shs[HID + col] = q_c[nt];
        }
    }
    __syncthreads();
    // coalesced C store: 16 rows x 128 cols x 2B = 4 KB = 256 threads x 16B
    {
        int row = t >> 4, off = t & 15;
        uint4 vv = *(const uint4*)(T + row * ZLD + off * 8);
        *(uint4*)(Cbf + (long)(tile * 16 + row) * HID + off * 8) = vv;
    }
    if (t < HID) {
        int grp = blockIdx.x & (NGRP - 1);
        float* base = stOutPart + (long)(grp * 256) * SSTR;
        atomicAdd(base + t * SSTR, shs[t]);
        atomicAdd(base + (HID + t) * SSTR, shs[HID + t]);
    }
}

// BN + gelu, bf16 in -> bf16 out, 16-group partial stats. Grid 2048.
__global__ __launch_bounds__(256) void bn_apply_part(const ushort* __restrict__ X,
                                                     ushort* __restrict__ Y,
                                                     const float* __restrict__ stPart,
                                                     const float* __restrict__ g,
                                                     const float* __restrict__ b) {
    __shared__ float scL[HID], sfL[HID];
    int t = threadIdx.x;
    if (t < HID) {
        float sm = 0.f, sq = 0.f;
#pragma unroll
        for (int gg = 0; gg < NGRP; ++gg) {
            sm += stPart[((long)gg * 256 + t) * SSTR];
            sq += stPart[((long)gg * 256 + HID + t) * SSTR];
        }
        const float invN = 1.0f / (float)N_NODES;
        float mean = sm * invN;
        float var = sq * invN - mean * mean;
        float s = g[t] * rsqrtf(var + 1e-5f);
        scL[t] = s;
        sfL[t] = b[t] - mean * s;
    }
    __syncthreads();
    int c8 = (t & 15) * 8;
    float sc[8], sf[8];
#pragma unroll
    for (int j = 0; j < 8; ++j) { sc[j] = scL[c8 + j]; sf[j] = sfL[c8 + j]; }
    int s0, s1;
    sub_range(blockIdx.x & 255, blockIdx.x >> 8, s0, s1);
    int c0 = s0 * 16, c1 = s1 * 16;
    for (int i = c0 + t; i < c1; i += 256) {
        Chunk ch;
        ch.u4 = ((const uint4*)X)[i];
#pragma unroll
        for (int j = 0; j < 8; ++j) {
            float f = bf2f(ch.us[j]) * sc[j] + sf[j];
            ch.us[j] = f2bf(gelu_fast(f));
        }
        ((uint4*)Y)[i] = ch.u4;
    }
}

// ---------------------------------------------------------------------------
// PERSISTENT FUSED MLP (control arm Q, r5-proven). z1/z2 in LDS, grouped
// stats, 2 fence-free grid barriers.
// ---------------------------------------------------------------------------
template <int NT>
__global__ __launch_bounds__(NT, 1) void fused_mlp(
    const ushort* __restrict__ Abf,
    const ushort* __restrict__ W1t, const ushort* __restrict__ W2t,
    const float* __restrict__ b1v, const float* __restrict__ b2v,
    const float* __restrict__ bn1g, const float* __restrict__ bn1b,
    const float* __restrict__ bn2g, const float* __restrict__ bn2b,
    float* __restrict__ st1, float* __restrict__ st2,
    ushort* __restrict__ Hl, int* __restrict__ bar) {
    constexpr int NW = NT / 64;       // waves per block
    constexpr int RSTEP = NW / 2;     // row-group count (tile stride)
    __shared__ __align__(16) ushort Z1[ZROWS * ZLD];
    __shared__ __align__(16) ushort Z2[ZROWS * ZLD];
    __shared__ float shs[2 * NT];
    __shared__ float scL[HID], sfL[HID];

    int t = threadIdx.x;
    int w = t >> 6, lane = t & 63;
    int m = lane & 15, q = lane >> 4;
    int c2 = w & 1, r2 = w >> 1;
    int t0 = (blockIdx.x * N_TILES) >> 8;
    int t1 = ((blockIdx.x + 1) * N_TILES) >> 8;
    int grp = blockIdx.x & (NGRP - 1);

    // -------- phase A: Z1 = A @ W1 + b1 --------
    bf16x8 Bf[4][4];
    {
        const ushort* Wh = W1t + (long)(c2 * 64) * HID;
#pragma unroll
        for (int nt = 0; nt < 4; ++nt)
#pragma unroll
            for (int kc = 0; kc < 4; ++kc)
                Bf[nt][kc] = *(const bf16x8*)(Wh + (nt * 16 + m) * HID + kc * 32 + q * 8);
    }
    float bias4[4];
#pragma unroll
    for (int nt = 0; nt < 4; ++nt) bias4[nt] = b1v[c2 * 64 + nt * 16 + m];

    float s_c[4] = {0, 0, 0, 0}, q_c[4] = {0, 0, 0, 0};
    int tile = t0 + r2;
    Chunk Ac[4];
    if (tile < t1) {
        const ushort* ar = Abf + (long)(tile * 16 + m) * HID + q * 8;
#pragma unroll
        for (int kc = 0; kc < 4; ++kc) Ac[kc].u4 = *(const uint4*)(ar + kc * 32);
    }
    while (tile < t1) {
        int nxt = tile + RSTEP;
        Chunk An[4];
        if (nxt < t1) {
            const ushort* ar = Abf + (long)(nxt * 16 + m) * HID + q * 8;
#pragma unroll
            for (int kc = 0; kc < 4; ++kc) An[kc].u4 = *(const uint4*)(ar + kc * 32);
        }
        f32x4 acc[4];
#pragma unroll
        for (int nt = 0; nt < 4; ++nt) acc[nt] = (f32x4){0.f, 0.f, 0.f, 0.f};
#pragma unroll
        for (int kc = 0; kc < 4; ++kc)
#pragma unroll
            for (int nt = 0; nt < 4; ++nt)
                acc[nt] = __builtin_amdgcn_mfma_f32_16x16x32_bf16(Ac[kc].v, Bf[nt][kc],
                                                                  acc[nt], 0, 0, 0);
        int lrow = (tile - t0) * 16;
#pragma unroll
        for (int nt = 0; nt < 4; ++nt) {
            int col = c2 * 64 + nt * 16 + m;
#pragma unroll
            for (int r = 0; r < 4; ++r) {
                float z = acc[nt][r] + bias4[nt];
                Z1[(lrow + q * 4 + r) * ZLD + col] = f2bf(z);
                s_c[nt] += z;
                q_c[nt] += z * z;
            }
        }
        tile = nxt;
#pragma unroll
        for (int kc = 0; kc < 4; ++kc) Ac[kc] = An[kc];
    }
#pragma unroll
    for (int nt = 0; nt < 4; ++nt) {
        s_c[nt] += __shfl_xor(s_c[nt], 16);
        s_c[nt] += __shfl_xor(s_c[nt], 32);
        q_c[nt] += __shfl_xor(q_c[nt], 16);
        q_c[nt] += __shfl_xor(q_c[nt], 32);
    }
    if (q == 0) {
#pragma unroll
        for (int nt = 0; nt < 4; ++nt) {
            shs[w * 64 + nt * 16 + m] = s_c[nt];
            shs[NT + w * 64 + nt * 16 + m] = q_c[nt];
        }
    }
    __syncthreads();
    if (t < HID) {
        int half = t >> 6, lc = t & 63;
        float a = 0.f, b = 0.f;
#pragma unroll
        for (int j = 0; j < RSTEP; ++j) {
            a += shs[(half + 2 * j) * 64 + lc];
            b += shs[NT + (half + 2 * j) * 64 + lc];
        }
        float* base = st1 + (long)(grp * 256) * SSTR;
        atomicAdd(base + t * SSTR, a);
        atomicAdd(base + (HID + t) * SSTR, b);
    }
    grid_sync(bar, 1);

    // BN1 coefficients via coherent loads (16-group sum)
    if (t < HID) {
        float sm = 0.f, sq = 0.f;
#pragma unroll
        for (int gg = 0; gg < NGRP; ++gg) {
            sm += coh_ld(st1 + ((long)gg * 256 + t) * SSTR);
            sq += coh_ld(st1 + ((long)gg * 256 + HID + t) * SSTR);
        }
        const float invN = 1.0f / (float)N_NODES;
        float mean = sm * invN;
        float var = sq * invN - mean * mean;
        float s = bn1g[t] * rsqrtf(var + 1e-5f);
        scL[t] = s;
        sfL[t] = bn1b[t] - mean * s;
    }
    __syncthreads();

    // -------- phase B: Z2 = gelu(bn1(Z1)) @ W2 + b2 --------
    {
        const ushort* Wh = W2t + (long)(c2 * 64) * HID;
#pragma unroll
        for (int nt = 0; nt < 4; ++nt)
#pragma unroll
            for (int kc = 0; kc < 4; ++kc)
                Bf[nt][kc] = *(const bf16x8*)(Wh + (nt * 16 + m) * HID + kc * 32 + q * 8);
    }
#pragma unroll
    for (int nt = 0; nt < 4; ++nt) bias4[nt] = b2v[c2 * 64 + nt * 16 + m];
#pragma unroll
    for (int nt = 0; nt < 4; ++nt) { s_c[nt] = 0.f; q_c[nt] = 0.f; }

    for (int tl = t0 + r2; tl < t1; tl += RSTEP) {
        int lrow = (tl - t0) * 16;
        Chunk Ax[4];
#pragma unroll
        for (int kc = 0; kc < 4; ++kc)
            Ax[kc].u4 = *(const uint4*)(Z1 + (lrow + m) * ZLD + kc * 32 + q * 8);
#pragma unroll
        for (int kc = 0; kc < 4; ++kc)
#pragma unroll
            for (int j = 0; j < 8; ++j) {
                int k = kc * 32 + q * 8 + j;
                float f = bf2f(Ax[kc].us[j]) * scL[k] + sfL[k];
                Ax[kc].us[j] = f2bf(gelu_fast(f));
            }
        f32x4 acc[4];
#pragma unroll
        for (int nt = 0; nt < 4; ++nt) acc[nt] = (f32x4){0.f, 0.f, 0.f, 0.f};
#pragma unroll
        for (int kc = 0; kc < 4; ++kc)
#pragma unroll
            for (int nt = 0; nt < 4; ++nt)
                acc[nt] = __builtin_amdgcn_mfma_f32_16x16x32_bf16(Ax[kc].v, Bf[nt][kc],
                                                                  acc[nt], 0, 0, 0);
#pragma unroll
        for (int nt = 0; nt < 4; ++nt) {
            int col = c2 * 64 + nt * 16 + m;
#pragma unroll
            for (int r = 0; r < 4; ++r) {
                float z = acc[nt][r] + bias4[nt];
                Z2[(lrow + q * 4 + r) * ZLD + col] = f2bf(z);
                s_c[nt] += z;
                q_c[nt] += z * z;
            }
        }
    }
#pragma unroll
    for (int nt = 0; nt < 4; ++nt) {
        s_c[nt] += __shfl_xor(s_c[nt], 16);
        s_c[nt] += __shfl_xor(s_c[nt], 32);
        q_c[nt] += __shfl_xor(q_c[nt], 16);
        q_c[nt] += __shfl_xor(q_c[nt], 32);
    }
    if (q == 0) {
#pragma unroll
        for (int nt = 0; nt < 4; ++nt) {
            shs[w * 64 + nt * 16 + m] = s_c[nt];
            shs[NT + w * 64 + nt * 16 + m] = q_c[nt];
        }
    }
    __syncthreads();
    if (t < HID) {
        int half = t >> 6, lc = t & 63;
        float a = 0.f, b = 0.f;
#pragma unroll
        for (int j = 0; j < RSTEP; ++j) {
            a += shs[(half + 2 * j) * 64 + lc];
            b += shs[NT + (half + 2 * j) * 64 + lc];
        }
        float* base = st2 + (long)(grp * 256) * SSTR;
        atomicAdd(base + t * SSTR, a);
        atomicAdd(base + (HID + t) * SSTR, b);
    }
    grid_sync(bar, 2);

    // BN2 coefficients (scL/sfL reuse safe: all waves past phase B)
    if (t < HID) {
        float sm = 0.f, sq = 0.f;
#pragma unroll
        for (int gg = 0; gg < NGRP; ++gg) {
            sm += coh_ld(st2 + ((long)gg * 256 + t) * SSTR);
            sq += coh_ld(st2 + ((long)gg * 256 + HID + t) * SSTR);
        }
        const float invN = 1.0f / (float)N_NODES;
        float mean = sm * invN;
        float var = sq * invN - mean * mean;
        float s = bn2g[t] * rsqrtf(var + 1e-5f);
        scL[t] = s;
        sfL[t] = bn2b[t] - mean * s;
    }
    __syncthreads();

    // -------- phase C: Hl = gelu(bn2(Z2)) -> global --------
    int nch = (t1 - t0) * 16 * 16;  // uint4 chunks (16 per row)
    for (int i = t; i < nch; i += NT) {
        int row = i >> 4, off = i & 15;
        Chunk ch;
        ch.u4 = *(const uint4*)(Z2 + row * ZLD + off * 8);
#pragma unroll
        for (int j = 0; j < 8; ++j) {
            int cc = off * 8 + j;
            float f = bf2f(ch.us[j]) * scL[cc] + sfL[cc];
            ch.us[j] = f2bf(gelu_fast(f));
        }
        *(uint4*)(Hl + (long)(t0 * 16 + row) * HID + off * 8) = ch.u4;
    }
}

// ---------------------------------------------------------------------------
// FUSED JK attention + pooling accumulation (restored: JK-in-persistent
// lost r8 — 79.5us fused vs ~74us split). Grid 2048 x 4 waves.
// ---------------------------------------------------------------------------
__global__ __launch_bounds__(256) void jk_pool(const ushort* __restrict__ H0,
                                               const ushort* __restrict__ H1,
                                               const ushort* __restrict__ H2,
                                               const ushort* __restrict__ H3,
                                               const float* __restrict__ att,
                                               const int* __restrict__ batch,
                                               float* __restrict__ psum,
                                               float* __restrict__ pmax) {
    int t = threadIdx.x;
    int lane = t & 63, w = t >> 6;
    long wid = (long)blockIdx.x * 4 + w;
    int a0 = (int)((wid * N_NODES) >> 13);
    int a1 = (int)(((wid + 1) * N_NODES) >> 13);
    const ushort* Hs[4] = {H0, H1, H2, H3};
    float2 av[4];
#pragma unroll
    for (int l = 0; l < 4; ++l) av[l] = *(const float2*)(att + l * HID + 2 * lane);

    int curg = -1;
    float sx = 0.f, sy = 0.f, mx = -INFINITY, my = -INFINITY;
    for (int node = a0; node < a1; ++node) {
        int g = batch[node];
        if (g != curg) {
            if (curg >= 0) {
                float* ps = psum + (long)curg * HID + 2 * lane;
                float* pm = pmax + (long)curg * HID + 2 * lane;
                atomicAdd(ps, sx);
                atomicAdd(ps + 1, sy);
                atomicMaxF(pm, mx);
                atomicMaxF(pm + 1, my);
            }
            curg = g;
            sx = 0.f; sy = 0.f; mx = -INFINITY; my = -INFINITY;
        }
        float hx[4], hy[4], scr[4];
#pragma unroll
        for (int l = 0; l < 4; ++l) {
            unsigned int u = *(const unsigned int*)(Hs[l] + (long)node * HID + 2 * lane);
            float vx = bf2f((ushort)(u & 0xFFFF));
            float vy = bf2f((ushort)(u >> 16));
            hx[l] = vx; hy[l] = vy;
            float p = vx * av[l].x + vy * av[l].y;
#pragma unroll
            for (int off = 32; off > 0; off >>= 1) p += __shfl_xor(p, off);
            scr[l] = p * (1.0f / HID);
        }
        float mm = fmaxf(fmaxf(scr[0], scr[1]), fmaxf(scr[2], scr[3]));
        float e[4], se = 0.f;
#pragma unroll
        for (int l = 0; l < 4; ++l) { e[l] = expf(scr[l] - mm); se += e[l]; }
        float inv = 1.0f / se;
        float ox = 0.f, oy = 0.f;
#pragma unroll
        for (int l = 0; l < 4; ++l) {
            float a = e[l] * inv;
            ox += a * hx[l];
            oy += a * hy[l];
        }
        sx += ox; sy += oy;
        mx = fmaxf(mx, ox); my = fmaxf(my, oy);
    }
    if (curg >= 0) {
        float* ps = psum + (long)curg * HID + 2 * lane;
        float* pm = pmax + (long)curg * HID + 2 * lane;
        atomicAdd(ps, sx);
        atomicAdd(ps + 1, sy);
        atomicMaxF(pm, mx);
        atomicMaxF(pm + 1, my);
    }
}

// ---------------------------------------------------------------------------
// Fused pool finalize + MLP head. Grid 512 x 128.
// ---------------------------------------------------------------------------
__global__ __launch_bounds__(128) void finalize_head(const float* __restrict__ psum,
                                                     const float* __restrict__ pmax,
                                                     const int* __restrict__ gstart,
                                                     const int* __restrict__ gend,
                                                     const float* __restrict__ pw,
                                                     const float* __restrict__ fcAw,
                                                     const float* __restrict__ fcAb,
                                                     const float* __restrict__ lng,
                                                     const float* __restrict__ lnb,
                                                     const float* __restrict__ fcBw,
                                                     const float* __restrict__ fcBb,
                                                     float* __restrict__ out) {
    __shared__ float p[HID], qv[HID], red[HID];
    int g = blockIdx.x, j = threadIdx.x;
    float w0 = pw[0], w1 = pw[1], w2 = pw[2];
    float mw = fmaxf(w0, fmaxf(w1, w2));
    float e0 = expf(w0 - mw), e1 = expf(w1 - mw), e2 = expf(w2 - mw);
    float inv = 1.0f / (e0 + e1 + e2);
    e0 *= inv; e1 *= inv; e2 *= inv;
    int cnt = gend[g] - gstart[g];
    float s = psum[g * HID + j];
    float mx = pmax[g * HID + j];
    float mean0 = cnt > 0 ? s / (float)cnt : 0.f;
    float mxv = cnt > 0 ? mx : 0.f;
    float pool = s * e0 + mean0 * e1 + mxv * e2;
    p[j] = pool;
    __syncthreads();
    float acc = fcAb[j];
    for (int k = 0; k < HID; ++k) acc += p[k] * fcAw[k * HID + j];
    red[j] = acc;
    __syncthreads();
    for (int off = 64; off > 0; off >>= 1) {
        if (j < off) red[j] += red[j + off];
        __syncthreads();
    }
    float mean = red[0] * (1.0f / HID);
    __syncthreads();
    float d = acc - mean;
    red[j] = d * d;
    __syncthreads();
    for (int off = 64; off > 0; off >>= 1) {
        if (j < off) red[j] += red[j + off];
        __syncthreads();
    }
    float var = red[0] * (1.0f / HID);
    float y = d * rsqrtf(var + 1e-5f) * lng[j] + lnb[j];
    qv[j] = gelu_exact(y) + pool;
    __syncthreads();
    if (j < LAT) {
        float o = fcBb[j];
        for (int k = 0; k < HID; ++k) o += qv[k] * fcBw[k * LAT + j];
        out[g * LAT + j] = o;
    }
}

extern "C" void kernel_launch(void* const* d_in, const int* in_sizes, int n_in,
                              void* d_out, int out_size, void* d_ws, size_t ws_size,
                              hipStream_t stream) {
    const float* x = (const float*)d_in[0];
    const int* ei = (const int*)d_in[1];
    const int* src = ei;
    const int* dst = ei + N_EDGES;
    const int* batch = (const int*)d_in[2];
    const float* ibn_g = (const float*)d_in[3];
    const float* ibn_b = (const float*)d_in[4];
    const float* eps = (const float*)d_in[5];
    const float* fc1w = (const float*)d_in[6];
    const float* fc1b = (const float*)d_in[7];
    const float* bn1g = (const float*)d_in[8];
    const float* bn1b = (const float*)d_in[9];
    const float* fc2w = (const float*)d_in[10];
    const float* fc2b = (const float*)d_in[11];
    const float* bng = (const float*)d_in[12];
    const float* bnb = (const float*)d_in[13];
    const float* att = (const float*)d_in[14];
    const float* pw = (const float*)d_in[15];
    const float* fcAw = (const float*)d_in[16];
    const float* fcAb = (const float*)d_in[17];
    const float* lng = (const float*)d_in[18];
    const float* lnb = (const float*)d_in[19];
    const float* fcBw = (const float*)d_in[20];
    const float* fcBb = (const float*)d_in[21];
    float* out = (float*)d_out;

    const size_t NH = (size_t)N_NODES * HID;
    char* w8 = (char*)d_ws;
    ushort* x0bf = (ushort*)w8;     w8 += NH * 2;
    ushort* hprebf = (ushort*)w8;   w8 += NH * 2;  // gather out / MLP in
    ushort* z1bf = (ushort*)w8;     w8 += NH * 2;  // arm P: GEMM1 out
    ushort* z2bf = (ushort*)w8;     w8 += NH * 2;  // arm P: GEMM2 out
    ushort* Hlbf[NL];
    for (int l = 0; l < NL; ++l) { Hlbf[l] = (ushort*)w8; w8 += NH * 2; }
    float* statsPart = (float*)w8;  w8 += (size_t)9 * PSET * 4;
    float* psum = (float*)w8;       w8 += (size_t)N_GRAPHS * HID * 4;
    float* pmax = (float*)w8;       w8 += (size_t)N_GRAPHS * HID * 4;
    int* gstart = (int*)w8;         w8 += N_GRAPHS * 4;
    int* gend = (int*)w8;           w8 += N_GRAPHS * 4;
    int* counts = (int*)w8;         w8 += N_NODES * 4;
    int* offs = (int*)w8;           w8 += N_NODES * 4;
    int* cursor = (int*)w8;         w8 += N_NODES * 4;
    int* bsum = (int*)w8;           w8 += 256 * 4;
    int* csr = (int*)w8;            w8 += (size_t)N_EDGES * 4;
    ushort* WtBf = (ushort*)w8;     w8 += (size_t)8 * HID * HID * 2;
    int* bar = (int*)w8;            w8 += 2048 * 4;  // 4 regions x 512 ints

    const int edgeBlocks = (N_EDGES + 255) / 256;  // 2344

    // 1: weights + all zero-init
    setup<<<512, 256, 0, stream>>>(fc1w, fc2w, WtBf, counts, statsPart,
                                   psum, pmax, gstart, gend, bar);
    // 2: input col-stats (grouped partials) + CSR degree count + graph ranges
    stats_count<<<256 + edgeBlocks + 196, 256, 0, stream>>>(x, statsPart, dst, counts,
                                                            batch, gstart, gend);
    // 3: input BN apply (fp32 -> bf16; 16-group stat sum) + scan pass 1
    bn_scan<<<2048, 256, 0, stream>>>(x, x0bf, statsPart, ibn_g, ibn_b, counts, offs,
                                      bsum);
    // 4: scan passes 2+3 -> offs, cursor
    scan23<<<196, 256, 0, stream>>>(offs, bsum, cursor);
    // 5: CSR fill
    csr_fill<<<edgeBlocks, 256, 0, stream>>>(src, dst, cursor, csr);

    // Occupancy A/B for the MLP: layers 0,2 -> non-persistent split path
    // (grid-3125 GEMMs, kernel-boundary sync); layers 1,3 -> persistent
    // fused_mlp (control). JK fusion reverted (lost r8).
    const ushort* xin = x0bf;
    for (int l = 0; l < NL; ++l) {
        float* p1 = statsPart + (size_t)(1 + 2 * l) * PSET;
        float* p2 = statsPart + (size_t)(2 + 2 * l) * PSET;
        gin_gather_bf<<<2048, 256, 0, stream>>>(xin, hprebf, offs, counts, csr, eps, l);
        if (l == 0 || l == 2) {
            gemm_np<<<N_TILES, 256, 0, stream>>>(hprebf, WtBf + (size_t)l * HID * HID,
                                                 fc1b + l * HID, z1bf,
                                                 nullptr, nullptr, nullptr, 0, p1);
            gemm_np<<<N_TILES, 256, 0, stream>>>(z1bf, WtBf + (size_t)(4 + l) * HID * HID,
                                                 fc2b + l * HID, z2bf,
                                                 p1, bn1g + l * HID, bn1b + l * HID, 1, p2);
            bn_apply_part<<<2048, 256, 0, stream>>>(z2bf, Hlbf[l], p2, bng + l * HID,
                                                    bnb + l * HID);
        } else {
            fused_mlp<512><<<256, 512, 0, stream>>>(
                hprebf, WtBf + (size_t)l * HID * HID,
                WtBf + (size_t)(4 + l) * HID * HID, fc1b + l * HID, fc2b + l * HID,
                bn1g + l * HID, bn1b + l * HID, bng + l * HID, bnb + l * HID,
                p1, p2, Hlbf[l], bar + l * 512);
        }
        xin = Hlbf[l];
    }

    jk_pool<<<2048, 256, 0, stream>>>(Hlbf[0], Hlbf[1], Hlbf[2], Hlbf[3], att, batch,
                                      psum, pmax);
    finalize_head<<<N_GRAPHS, 128, 0, stream>>>(psum, pmax, gstart, gend, pw, fcAw,
                                                fcAb, lng, lnb, fcBw, fcBb, out);
}

// Round 10
// 480.135 us; speedup vs baseline: 1.3565x; 1.3565x over previous
//
#include <hip/hip_runtime.h>
#include <math.h>

#define N_NODES 50000
#define N_EDGES 600000
#define N_GRAPHS 512
#define HID 128
#define LAT 64
#define NL 4
#define SSTR 16        // stats padding: 1 float per 64B cache line
#define NGRP 16        // stat/barrier groups
#define PSET (NGRP * 256 * SSTR)  // floats per partial stat set: 65536
#define N_TILES 3125   // 16-row tiles, exact
#define ZROWS 208      // max rows per persistent block: ceil(3125/256)*16
#define ZLD 136        // LDS z-tile row stride in ushorts (128 + 8 pad)

typedef __attribute__((ext_vector_type(8))) __bf16 bf16x8;
typedef __attribute__((ext_vector_type(4))) float f32x4;

union Chunk {
    bf16x8 v;
    uint4 u4;
    ushort us[8];
};

__device__ __forceinline__ float gelu_exact(float x) {
    return 0.5f * x * (1.0f + erff(x * 0.70710678118654752f));
}
// Branchless gelu via A&S 7.1.26 erf poly (|err| <= 1.5e-7) + fast exp/rcp.
__device__ __forceinline__ float gelu_fast(float x) {
    float ax = fabsf(x) * 0.70710678118654752f;
    float t = __builtin_amdgcn_rcpf(fmaf(0.3275911f, ax, 1.0f));
    float p = t * (0.254829592f +
              t * (-0.284496736f +
              t * (1.421413741f +
              t * (-1.453152027f + t * 1.061405429f))));
    float e = __expf(-ax * ax);
    float erfv = 1.0f - p * e;
    float erfs = copysignf(erfv, x);
    return 0.5f * x * (1.0f + erfs);
}
__device__ __forceinline__ float bf2f(ushort h) {
    return __uint_as_float(((unsigned int)h) << 16);
}
__device__ __forceinline__ ushort f2bf(float f) {  // RNE
    unsigned int u = __float_as_uint(f);
    unsigned int r = (u + 0x7FFFu + ((u >> 16) & 1u)) >> 16;
    return (ushort)r;
}
// float atomic max via sign trick (init to -inf)
__device__ __forceinline__ void atomicMaxF(float* addr, float v) {
    if (v >= 0.f) atomicMax((int*)addr, __float_as_int(v));
    else atomicMin((unsigned int*)addr, __float_as_uint(v));
}

// Canonical row partition p (0..255) -> sub-chunk j (0..7) -> [s0, s1)
__device__ __forceinline__ void sub_range(int p, int j, int& s0, int& s1) {
    int r0 = (p * N_NODES) >> 8;
    int r1 = ((p + 1) * N_NODES) >> 8;
    int len = r1 - r0;
    s0 = r0 + ((len * j) >> 3);
    s1 = r0 + ((len * (j + 1)) >> 3);
}

// Grouped fence-free grid barrier (mechanism cost ~1.2-2.3us/barrier, r6).
// Region layout (ints): [64+g*16] group counters, [320] master, [336] flag.
__device__ __forceinline__ void grid_sync(int* bar, int epoch) {
    __syncthreads();
    if (threadIdx.x == 0) {
        int g = blockIdx.x & (NGRP - 1);
        int prev = __hip_atomic_fetch_add(bar + 64 + g * 16, 1, __ATOMIC_RELAXED,
                                          __HIP_MEMORY_SCOPE_AGENT);
        if (prev == NGRP * epoch - 1) {  // last of my group this epoch
            int mp = __hip_atomic_fetch_add(bar + 320, 1, __ATOMIC_RELAXED,
                                            __HIP_MEMORY_SCOPE_AGENT);
            if (mp == NGRP * epoch - 1)  // last group overall
                __hip_atomic_store(bar + 336, epoch, __ATOMIC_RELAXED,
                                   __HIP_MEMORY_SCOPE_AGENT);
        }
        while (__hip_atomic_load(bar + 336, __ATOMIC_RELAXED,
                                 __HIP_MEMORY_SCOPE_AGENT) < epoch)
            __builtin_amdgcn_s_sleep(4);
    }
    __syncthreads();
    asm volatile("" ::: "memory");  // pin compiler ordering of post-barrier loads
}

// coherent (agent-scope) float load, bypasses incoherent L1/L2
__device__ __forceinline__ float coh_ld(const float* p) {
    return __hip_atomic_load((const float*)p, __ATOMIC_RELAXED, __HIP_MEMORY_SCOPE_AGENT);
}

// ---------------------------------------------------------------------------
// Fused setup: weight pre-transpose + zero counts/partial-stats + pool/
// barrier init. Grid 512x256.
// ---------------------------------------------------------------------------
__global__ __launch_bounds__(256) void setup(const float* __restrict__ fc1w,
                                             const float* __restrict__ fc2w,
                                             ushort* __restrict__ Wt,
                                             int* __restrict__ counts,
                                             float* __restrict__ statsPart,
                                             float* __restrict__ psum,
                                             float* __restrict__ pmax,
                                             int* __restrict__ gstart,
                                             int* __restrict__ gend,
                                             int* __restrict__ bar) {
    int i = blockIdx.x * 256 + threadIdx.x;  // always < 131072 == 8*HID*HID
    {
        int g = i >> 14;
        int rem = i & 16383;
        int n = rem >> 7, k = rem & 127;
        const float* W = (g < 4) ? (fc1w + (long)g * HID * HID)
                                 : (fc2w + (long)(g - 4) * HID * HID);
        Wt[i] = f2bf(W[k * HID + n]);
    }
    if (i < N_NODES) counts[i] = 0;
    for (long j = i; j < (long)9 * PSET; j += 131072) statsPart[j] = 0.f;
    if (i < N_GRAPHS * HID) { psum[i] = 0.f; pmax[i] = -INFINITY; }
    if (i < N_GRAPHS) { gstart[i] = 0; gend[i] = 0; }
    if (i < 2048) bar[i] = 0;
}

// ---------------------------------------------------------------------------
// Fused: col stats over fp32 X (blocks 0..255, grouped partial writes) +
// CSR degree count (256..2599) + graph ranges (2600..2795). Grid 2796.
// ---------------------------------------------------------------------------
__global__ __launch_bounds__(256) void stats_count(const float* __restrict__ X,
                                                   float* __restrict__ inPart,
                                                   const int* __restrict__ dst,
                                                   int* __restrict__ counts,
                                                   const int* __restrict__ batch,
                                                   int* __restrict__ gstart,
                                                   int* __restrict__ gend) {
    __shared__ float sh[2048];
    int bx = blockIdx.x;
    int t = threadIdx.x;
    if (bx < 256) {
        int tx = t & 31, ty = t >> 5;
        float s[4] = {0, 0, 0, 0}, q[4] = {0, 0, 0, 0};
        const int nTiles = (N_NODES + 63) / 64;  // 782
        for (int tile = bx; tile < nTiles; tile += 256) {
            int r0 = tile * 64;
#pragma unroll
            for (int i = 0; i < 8; ++i) {
                int r = r0 + ty + 8 * i;
                int rc = min(r, N_NODES - 1);
                float4 v = *(const float4*)(X + (long)rc * HID + 4 * tx);
                float w = (r < N_NODES) ? 1.f : 0.f;
                float x0 = v.x * w, x1 = v.y * w, x2 = v.z * w, x3 = v.w * w;
                s[0] += x0; s[1] += x1; s[2] += x2; s[3] += x3;
                q[0] += x0 * v.x; q[1] += x1 * v.y; q[2] += x2 * v.z; q[3] += x3 * v.w;
            }
        }
#pragma unroll
        for (int c = 0; c < 4; ++c) {
            sh[ty * HID + 4 * tx + c] = s[c];
            sh[1024 + ty * HID + 4 * tx + c] = q[c];
        }
        __syncthreads();
        if (ty == 0) {
            int grp = bx & (NGRP - 1);
            float* base = inPart + (long)(grp * 256) * SSTR;
#pragma unroll
            for (int c = 0; c < 4; ++c) {
                float a = 0, b = 0;
#pragma unroll
                for (int j = 0; j < 8; ++j) {
                    a += sh[j * HID + 4 * tx + c];
                    b += sh[1024 + j * HID + 4 * tx + c];
                }
                atomicAdd(base + (4 * tx + c) * SSTR, a);
                atomicAdd(base + (HID + 4 * tx + c) * SSTR, b);
            }
        }
    } else if (bx < 2600) {
        int e = (bx - 256) * 256 + t;
        if (e < N_EDGES) atomicAdd(counts + dst[e], 1);
    } else {
        int n = (bx - 2600) * 256 + t;
        if (n < N_NODES) {
            int b = batch[n];
            if (n == 0 || batch[n - 1] != b) gstart[b] = n;
            if (n == N_NODES - 1 || batch[n + 1] != b) gend[b] = n + 1;
        }
    }
}

// ---------------------------------------------------------------------------
// Fused: input-BN apply fp32->bf16 + scan pass 1 over counts (blocks 0..195).
// ---------------------------------------------------------------------------
__global__ __launch_bounds__(256) void bn_scan(const float* __restrict__ X,
                                               ushort* __restrict__ Y,
                                               const float* __restrict__ inPart,
                                               const float* __restrict__ g,
                                               const float* __restrict__ b,
                                               const int* __restrict__ counts,
                                               int* __restrict__ offs,
                                               int* __restrict__ bsum) {
    __shared__ float scL[HID], sfL[HID];
    __shared__ int shI[256];
    int t = threadIdx.x;
    if (t < HID) {
        float sm = 0.f, sq = 0.f;
#pragma unroll
        for (int gg = 0; gg < NGRP; ++gg) {
            sm += inPart[((long)gg * 256 + t) * SSTR];
            sq += inPart[((long)gg * 256 + HID + t) * SSTR];
        }
        const float invN = 1.0f / (float)N_NODES;
        float mean = sm * invN;
        float var = sq * invN - mean * mean;
        float s = g[t] * rsqrtf(var + 1e-5f);
        scL[t] = s;
        sfL[t] = b[t] - mean * s;
    }
    __syncthreads();
    int c4 = (t & 31) * 4;
    float sc[4], sf[4];
#pragma unroll
    for (int j = 0; j < 4; ++j) { sc[j] = scL[c4 + j]; sf[j] = sfL[c4 + j]; }
    int s0, s1;
    sub_range(blockIdx.x & 255, blockIdx.x >> 8, s0, s1);
    int c0 = s0 * 32, c1 = s1 * 32;
    for (int i = c0 + t; i < c1; i += 256) {
        float4 v = ((const float4*)X)[i];
        ushort4 w;
        w.x = f2bf(v.x * sc[0] + sf[0]);
        w.y = f2bf(v.y * sc[1] + sf[1]);
        w.z = f2bf(v.z * sc[2] + sf[2]);
        w.w = f2bf(v.w * sc[3] + sf[3]);
        ((ushort4*)Y)[i] = w;
    }
    // scan pass 1 (block-local exclusive scan + block totals)
    if (blockIdx.x < 196) {
        int i = blockIdx.x * 256 + t;
        int v = (i < N_NODES) ? counts[i] : 0;
        shI[t] = v;
        __syncthreads();
        for (int off = 1; off < 256; off <<= 1) {
            int a = (t >= off) ? shI[t - off] : 0;
            __syncthreads();
            shI[t] += a;
            __syncthreads();
        }
        if (i < N_NODES) offs[i] = shI[t] - v;
        if (t == 255) bsum[blockIdx.x] = shI[255];
    }
}

// ---------------------------------------------------------------------------
// Scan passes 2+3 fused. Writes offs + PADDED cursor (one counter per 64B
// line: csr_fill's value-returning atomics on packed lines serialize
// ~192-deep per line; padding spreads them to ~12-deep — r9 lesson).
// ---------------------------------------------------------------------------
__global__ __launch_bounds__(256) void scan23(int* __restrict__ offs,
                                              const int* __restrict__ bsum,
                                              int* __restrict__ cursorPad) {
    __shared__ int sh[256];
    int t = threadIdx.x, bx = blockIdx.x;
    int v = (t < bx) ? bsum[t] : 0;
    sh[t] = v;
    __syncthreads();
    for (int off = 128; off > 0; off >>= 1) {
        if (t < off) sh[t] += sh[t + off];
        __syncthreads();
    }
    int pre = sh[0];
    int i = bx * 256 + t;
    if (i < N_NODES) {
        int o = offs[i] + pre;
        offs[i] = o;
        cursorPad[(long)i * SSTR] = o;
    }
}

__global__ __launch_bounds__(256) void csr_fill(const int* __restrict__ src,
                                                const int* __restrict__ dst,
                                                int* __restrict__ cursorPad,
                                                int* __restrict__ csr) {
    int e = blockIdx.x * blockDim.x + threadIdx.x;
    if (e >= N_EDGES) return;
    int pos = atomicAdd(cursorPad + (long)dst[e] * SSTR, 1);
    csr[pos] = src[e];
}

// ---------------------------------------------------------------------------
// Dedicated GIN aggregation (fusing it into the persistent kernel LOST r7:
// 8 waves/CU is latency-starved for streaming work). Grid 2048.
// ---------------------------------------------------------------------------
__global__ __launch_bounds__(256) void gin_gather_bf(const ushort* __restrict__ Xbf,
                                                     ushort* __restrict__ Hp,
                                                     const int* __restrict__ offs,
                                                     const int* __restrict__ counts,
                                                     const int* __restrict__ csr,
                                                     const float* __restrict__ eps, int l) {
    int t = threadIdx.x;
    int tx = t & 31;
    int grp = t >> 5;
    int s0, s1;
    sub_range(blockIdx.x & 255, blockIdx.x >> 8, s0, s1);
    float ev = 1.0f + eps[l];
    for (int node = s0 + grp; node < s1; node += 8) {
        ushort4 sv = *(const ushort4*)(Xbf + (long)node * HID + 4 * tx);
        float a0 = bf2f(sv.x) * ev, a1 = bf2f(sv.y) * ev;
        float a2 = bf2f(sv.z) * ev, a3 = bf2f(sv.w) * ev;
        int o = offs[node];
        int d = counts[node];
        int k = 0;
        for (; k + 8 <= d; k += 8) {
            int si[8];
#pragma unroll
            for (int j = 0; j < 8; ++j) si[j] = csr[o + k + j];
            ushort4 v[8];
#pragma unroll
            for (int j = 0; j < 8; ++j)
                v[j] = *(const ushort4*)(Xbf + (long)si[j] * HID + 4 * tx);
#pragma unroll
            for (int j = 0; j < 8; ++j) {
                a0 += bf2f(v[j].x); a1 += bf2f(v[j].y);
                a2 += bf2f(v[j].z); a3 += bf2f(v[j].w);
            }
        }
        for (; k + 4 <= d; k += 4) {
            int si[4];
#pragma unroll
            for (int j = 0; j < 4; ++j) si[j] = csr[o + k + j];
#pragma unroll
            for (int j = 0; j < 4; ++j) {
                ushort4 v = *(const ushort4*)(Xbf + (long)si[j] * HID + 4 * tx);
                a0 += bf2f(v.x); a1 += bf2f(v.y); a2 += bf2f(v.z); a3 += bf2f(v.w);
            }
        }
        for (; k < d; ++k) {
            int s = csr[o + k];
            ushort4 v = *(const ushort4*)(Xbf + (long)s * HID + 4 * tx);
            a0 += bf2f(v.x); a1 += bf2f(v.y); a2 += bf2f(v.z); a3 += bf2f(v.w);
        }
        ushort4 w;
        w.x = f2bf(a0); w.y = f2bf(a1); w.z = f2bf(a2); w.w = f2bf(a3);
        *(ushort4*)(Hp + (long)node * HID + 4 * tx) = w;
    }
}

// ---------------------------------------------------------------------------
// PERSISTENT FUSED MLP (champion, r8 = 489us). JK=true (layer 3 only):
// phase C computes H3 in-register from LDS Z2 and fuses the JK attention +
// pooling accumulation. Layers 0-2: JK=false, phase C stores Hl.
// ---------------------------------------------------------------------------
template <int NT, bool JK>
__global__ __launch_bounds__(NT, 1) void fused_mlp(
    const ushort* __restrict__ Abf,
    const ushort* __restrict__ W1t, const ushort* __restrict__ W2t,
    const float* __restrict__ b1v, const float* __restrict__ b2v,
    const float* __restrict__ bn1g, const float* __restrict__ bn1b,
    const float* __restrict__ bn2g, const float* __restrict__ bn2b,
    float* __restrict__ st1, float* __restrict__ st2,
    ushort* __restrict__ Hl, int* __restrict__ bar,
    const ushort* __restrict__ H0, const ushort* __restrict__ H1,
    const ushort* __restrict__ H2, const float* __restrict__ att,
    const int* __restrict__ batch, float* __restrict__ psum,
    float* __restrict__ pmax) {
    constexpr int NW = NT / 64;       // waves per block
    constexpr int RSTEP = NW / 2;     // row-group count (tile stride)
    __shared__ __align__(16) ushort Z1[ZROWS * ZLD];
    __shared__ __align__(16) ushort Z2[ZROWS * ZLD];
    __shared__ float shs[2 * NT];
    __shared__ float scL[HID], sfL[HID];

    int t = threadIdx.x;
    int w = t >> 6, lane = t & 63;
    int m = lane & 15, q = lane >> 4;
    int c2 = w & 1, r2 = w >> 1;
    int t0 = (blockIdx.x * N_TILES) >> 8;
    int t1 = ((blockIdx.x + 1) * N_TILES) >> 8;
    int grp = blockIdx.x & (NGRP - 1);

    // -------- phase A: Z1 = A @ W1 + b1 (global A, next-tile prefetch) -----
    bf16x8 Bf[4][4];
    {
        const ushort* Wh = W1t + (long)(c2 * 64) * HID;
#pragma unroll
        for (int nt = 0; nt < 4; ++nt)
#pragma unroll
            for (int kc = 0; kc < 4; ++kc)
                Bf[nt][kc] = *(const bf16x8*)(Wh + (nt * 16 + m) * HID + kc * 32 + q * 8);
    }
    float bias4[4];
#pragma unroll
    for (int nt = 0; nt < 4; ++nt) bias4[nt] = b1v[c2 * 64 + nt * 16 + m];

    float s_c[4] = {0, 0, 0, 0}, q_c[4] = {0, 0, 0, 0};
    int tile = t0 + r2;
    Chunk Ac[4];
    if (tile < t1) {
        const ushort* ar = Abf + (long)(tile * 16 + m) * HID + q * 8;
#pragma unroll
        for (int kc = 0; kc < 4; ++kc) Ac[kc].u4 = *(const uint4*)(ar + kc * 32);
    }
    while (tile < t1) {
        int nxt = tile + RSTEP;
        Chunk An[4];
        if (nxt < t1) {
            const ushort* ar = Abf + (long)(nxt * 16 + m) * HID + q * 8;
#pragma unroll
            for (int kc = 0; kc < 4; ++kc) An[kc].u4 = *(const uint4*)(ar + kc * 32);
        }
        f32x4 acc[4];
#pragma unroll
        for (int nt = 0; nt < 4; ++nt) acc[nt] = (f32x4){0.f, 0.f, 0.f, 0.f};
#pragma unroll
        for (int kc = 0; kc < 4; ++kc)
#pragma unroll
            for (int nt = 0; nt < 4; ++nt)
                acc[nt] = __builtin_amdgcn_mfma_f32_16x16x32_bf16(Ac[kc].v, Bf[nt][kc],
                                                                  acc[nt], 0, 0, 0);
        int lrow = (tile - t0) * 16;
#pragma unroll
        for (int nt = 0; nt < 4; ++nt) {
            int col = c2 * 64 + nt * 16 + m;
#pragma unroll
            for (int r = 0; r < 4; ++r) {
                float z = acc[nt][r] + bias4[nt];
                Z1[(lrow + q * 4 + r) * ZLD + col] = f2bf(z);
                s_c[nt] += z;
                q_c[nt] += z * z;
            }
        }
        tile = nxt;
#pragma unroll
        for (int kc = 0; kc < 4; ++kc) Ac[kc] = An[kc];
    }
#pragma unroll
    for (int nt = 0; nt < 4; ++nt) {
        s_c[nt] += __shfl_xor(s_c[nt], 16);
        s_c[nt] += __shfl_xor(s_c[nt], 32);
        q_c[nt] += __shfl_xor(q_c[nt], 16);
        q_c[nt] += __shfl_xor(q_c[nt], 32);
    }
    if (q == 0) {
#pragma unroll
        for (int nt = 0; nt < 4; ++nt) {
            shs[w * 64 + nt * 16 + m] = s_c[nt];
            shs[NT + w * 64 + nt * 16 + m] = q_c[nt];
        }
    }
    __syncthreads();
    if (t < HID) {
        int half = t >> 6, lc = t & 63;
        float a = 0.f, b = 0.f;
#pragma unroll
        for (int j = 0; j < RSTEP; ++j) {
            a += shs[(half + 2 * j) * 64 + lc];
            b += shs[NT + (half + 2 * j) * 64 + lc];
        }
        float* base = st1 + (long)(grp * 256) * SSTR;
        atomicAdd(base + t * SSTR, a);
        atomicAdd(base + (HID + t) * SSTR, b);
    }
    grid_sync(bar, 1);

    // BN1 coefficients via coherent loads (16-group sum)
    if (t < HID) {
        float sm = 0.f, sq = 0.f;
#pragma unroll
        for (int gg = 0; gg < NGRP; ++gg) {
            sm += coh_ld(st1 + ((long)gg * 256 + t) * SSTR);
            sq += coh_ld(st1 + ((long)gg * 256 + HID + t) * SSTR);
        }
        const float invN = 1.0f / (float)N_NODES;
        float mean = sm * invN;
        float var = sq * invN - mean * mean;
        float s = bn1g[t] * rsqrtf(var + 1e-5f);
        scL[t] = s;
        sfL[t] = bn1b[t] - mean * s;
    }
    __syncthreads();

    // -------- phase B: Z2 = gelu(bn1(Z1)) @ W2 + b2 --------
    {
        const ushort* Wh = W2t + (long)(c2 * 64) * HID;
#pragma unroll
        for (int nt = 0; nt < 4; ++nt)
#pragma unroll
            for (int kc = 0; kc < 4; ++kc)
                Bf[nt][kc] = *(const bf16x8*)(Wh + (nt * 16 + m) * HID + kc * 32 + q * 8);
    }
#pragma unroll
    for (int nt = 0; nt < 4; ++nt) bias4[nt] = b2v[c2 * 64 + nt * 16 + m];
#pragma unroll
    for (int nt = 0; nt < 4; ++nt) { s_c[nt] = 0.f; q_c[nt] = 0.f; }

    for (int tl = t0 + r2; tl < t1; tl += RSTEP) {
        int lrow = (tl - t0) * 16;
        Chunk Ax[4];
#pragma unroll
        for (int kc = 0; kc < 4; ++kc)
            Ax[kc].u4 = *(const uint4*)(Z1 + (lrow + m) * ZLD + kc * 32 + q * 8);
#pragma unroll
        for (int kc = 0; kc < 4; ++kc)
#pragma unroll
            for (int j = 0; j < 8; ++j) {
                int k = kc * 32 + q * 8 + j;
                float f = bf2f(Ax[kc].us[j]) * scL[k] + sfL[k];
                Ax[kc].us[j] = f2bf(gelu_fast(f));
            }
        f32x4 acc[4];
#pragma unroll
        for (int nt = 0; nt < 4; ++nt) acc[nt] = (f32x4){0.f, 0.f, 0.f, 0.f};
#pragma unroll
        for (int kc = 0; kc < 4; ++kc)
#pragma unroll
            for (int nt = 0; nt < 4; ++nt)
                acc[nt] = __builtin_amdgcn_mfma_f32_16x16x32_bf16(Ax[kc].v, Bf[nt][kc],
                                                                  acc[nt], 0, 0, 0);
#pragma unroll
        for (int nt = 0; nt < 4; ++nt) {
            int col = c2 * 64 + nt * 16 + m;
#pragma unroll
            for (int r = 0; r < 4; ++r) {
                float z = acc[nt][r] + bias4[nt];
                Z2[(lrow + q * 4 + r) * ZLD + col] = f2bf(z);
                s_c[nt] += z;
                q_c[nt] += z * z;
            }
        }
    }
#pragma unroll
    for (int nt = 0; nt < 4; ++nt) {
        s_c[nt] += __shfl_xor(s_c[nt], 16);
        s_c[nt] += __shfl_xor(s_c[nt], 32);
        q_c[nt] += __shfl_xor(q_c[nt], 16);
        q_c[nt] += __shfl_xor(q_c[nt], 32);
    }
    if (q == 0) {
#pragma unroll
        for (int nt = 0; nt < 4; ++nt) {
            shs[w * 64 + nt * 16 + m] = s_c[nt];
            shs[NT + w * 64 + nt * 16 + m] = q_c[nt];
        }
    }
    __syncthreads();
    if (t < HID) {
        int half = t >> 6, lc = t & 63;
        float a = 0.f, b = 0.f;
#pragma unroll
        for (int j = 0; j < RSTEP; ++j) {
            a += shs[(half + 2 * j) * 64 + lc];
            b += shs[NT + (half + 2 * j) * 64 + lc];
        }
        float* base = st2 + (long)(grp * 256) * SSTR;
        atomicAdd(base + t * SSTR, a);
        atomicAdd(base + (HID + t) * SSTR, b);
    }
    grid_sync(bar, 2);

    // BN2 coefficients (scL/sfL reuse safe: all waves past phase B)
    if (t < HID) {
        float sm = 0.f, sq = 0.f;
#pragma unroll
        for (int gg = 0; gg < NGRP; ++gg) {
            sm += coh_ld(st2 + ((long)gg * 256 + t) * SSTR);
            sq += coh_ld(st2 + ((long)gg * 256 + HID + t) * SSTR);
        }
        const float invN = 1.0f / (float)N_NODES;
        float mean = sm * invN;
        float var = sq * invN - mean * mean;
        float s = bn2g[t] * rsqrtf(var + 1e-5f);
        scL[t] = s;
        sfL[t] = bn2b[t] - mean * s;
    }
    __syncthreads();

    if (!JK) {
        // -------- phase C: Hl = gelu(bn2(Z2)) -> global --------
        int nch = (t1 - t0) * 16 * 16;  // uint4 chunks (16 per row)
        for (int i = t; i < nch; i += NT) {
            int row = i >> 4, off = i & 15;
            Chunk ch;
            ch.u4 = *(const uint4*)(Z2 + row * ZLD + off * 8);
#pragma unroll
            for (int j = 0; j < 8; ++j) {
                int cc = off * 8 + j;
                float f = bf2f(ch.us[j]) * scL[cc] + sfL[cc];
                ch.us[j] = f2bf(gelu_fast(f));
            }
            *(uint4*)(Hl + (long)(t0 * 16 + row) * HID + off * 8) = ch.u4;
        }
    } else {
        // -------- phase C-JK: H3 in-register + JK attention + pooling -----
        float2 av[4];
#pragma unroll
        for (int l = 0; l < 4; ++l) av[l] = *(const float2*)(att + l * HID + 2 * lane);
        int nrows = (t1 - t0) * 16;
        int wr0 = (w * nrows) / NW;
        int wr1 = ((w + 1) * nrows) / NW;
        int base = t0 * 16;
        int c = 2 * lane;
        float sA = scL[c], sB = scL[c + 1], fA = sfL[c], fB = sfL[c + 1];
        int curg = -1;
        float sx = 0.f, sy = 0.f, mx = -INFINITY, my = -INFINITY;
        for (int r = wr0; r < wr1; ++r) {
            int node = base + r;
            int g = batch[node];
            if (g != curg) {
                if (curg >= 0) {
                    float* ps = psum + (long)curg * HID + c;
                    float* pm = pmax + (long)curg * HID + c;
                    atomicAdd(ps, sx);
                    atomicAdd(ps + 1, sy);
                    atomicMaxF(pm, mx);
                    atomicMaxF(pm + 1, my);
                }
                curg = g;
                sx = 0.f; sy = 0.f; mx = -INFINITY; my = -INFINITY;
            }
            float f0 = bf2f(Z2[r * ZLD + c]) * sA + fA;
            float f1 = bf2f(Z2[r * ZLD + c + 1]) * sB + fB;
            float hx3 = bf2f(f2bf(gelu_fast(f0)));
            float hy3 = bf2f(f2bf(gelu_fast(f1)));
            unsigned u0 = *(const unsigned*)(H0 + (long)node * HID + c);
            unsigned u1 = *(const unsigned*)(H1 + (long)node * HID + c);
            unsigned u2 = *(const unsigned*)(H2 + (long)node * HID + c);
            float hx[4], hy[4];
            hx[0] = bf2f((ushort)(u0 & 0xFFFF)); hy[0] = bf2f((ushort)(u0 >> 16));
            hx[1] = bf2f((ushort)(u1 & 0xFFFF)); hy[1] = bf2f((ushort)(u1 >> 16));
            hx[2] = bf2f((ushort)(u2 & 0xFFFF)); hy[2] = bf2f((ushort)(u2 >> 16));
            hx[3] = hx3; hy[3] = hy3;
            float scr[4];
#pragma unroll
            for (int l = 0; l < 4; ++l) {
                float p = hx[l] * av[l].x + hy[l] * av[l].y;
#pragma unroll
                for (int off = 32; off > 0; off >>= 1) p += __shfl_xor(p, off);
                scr[l] = p * (1.0f / HID);
            }
            float mm = fmaxf(fmaxf(scr[0], scr[1]), fmaxf(scr[2], scr[3]));
            float e[4], se = 0.f;
#pragma unroll
            for (int l = 0; l < 4; ++l) { e[l] = expf(scr[l] - mm); se += e[l]; }
            float inv = 1.0f / se;
            float ox = 0.f, oy = 0.f;
#pragma unroll
            for (int l = 0; l < 4; ++l) {
                float a = e[l] * inv;
                ox += a * hx[l];
                oy += a * hy[l];
            }
            sx += ox; sy += oy;
            mx = fmaxf(mx, ox); my = fmaxf(my, oy);
        }
        if (curg >= 0) {
            float* ps = psum + (long)curg * HID + c;
            float* pm = pmax + (long)curg * HID + c;
            atomicAdd(ps, sx);
            atomicAdd(ps + 1, sy);
            atomicMaxF(pm, mx);
            atomicMaxF(pm + 1, my);
        }
    }
}

// ---------------------------------------------------------------------------
// Fused pool finalize + MLP head. Grid 512 x 128.
// ---------------------------------------------------------------------------
__global__ __launch_bounds__(128) void finalize_head(const float* __restrict__ psum,
                                                     const float* __restrict__ pmax,
                                                     const int* __restrict__ gstart,
                                                     const int* __restrict__ gend,
                                                     const float* __restrict__ pw,
                                                     const float* __restrict__ fcAw,
                                                     const float* __restrict__ fcAb,
                                                     const float* __restrict__ lng,
                                                     const float* __restrict__ lnb,
                                                     const float* __restrict__ fcBw,
                                                     const float* __restrict__ fcBb,
                                                     float* __restrict__ out) {
    __shared__ float p[HID], qv[HID], red[HID];
    int g = blockIdx.x, j = threadIdx.x;
    float w0 = pw[0], w1 = pw[1], w2 = pw[2];
    float mw = fmaxf(w0, fmaxf(w1, w2));
    float e0 = expf(w0 - mw), e1 = expf(w1 - mw), e2 = expf(w2 - mw);
    float inv = 1.0f / (e0 + e1 + e2);
    e0 *= inv; e1 *= inv; e2 *= inv;
    int cnt = gend[g] - gstart[g];
    float s = psum[g * HID + j];
    float mx = pmax[g * HID + j];
    float mean0 = cnt > 0 ? s / (float)cnt : 0.f;
    float mxv = cnt > 0 ? mx : 0.f;
    float pool = s * e0 + mean0 * e1 + mxv * e2;
    p[j] = pool;
    __syncthreads();
    float acc = fcAb[j];
    for (int k = 0; k < HID; ++k) acc += p[k] * fcAw[k * HID + j];
    red[j] = acc;
    __syncthreads();
    for (int off = 64; off > 0; off >>= 1) {
        if (j < off) red[j] += red[j + off];
        __syncthreads();
    }
    float mean = red[0] * (1.0f / HID);
    __syncthreads();
    float d = acc - mean;
    red[j] = d * d;
    __syncthreads();
    for (int off = 64; off > 0; off >>= 1) {
        if (j < off) red[j] += red[j + off];
        __syncthreads();
    }
    float var = red[0] * (1.0f / HID);
    float y = d * rsqrtf(var + 1e-5f) * lng[j] + lnb[j];
    qv[j] = gelu_exact(y) + pool;
    __syncthreads();
    if (j < LAT) {
        float o = fcBb[j];
        for (int k = 0; k < HID; ++k) o += qv[k] * fcBw[k * LAT + j];
        out[g * LAT + j] = o;
    }
}

extern "C" void kernel_launch(void* const* d_in, const int* in_sizes, int n_in,
                              void* d_out, int out_size, void* d_ws, size_t ws_size,
                              hipStream_t stream) {
    const float* x = (const float*)d_in[0];
    const int* ei = (const int*)d_in[1];
    const int* src = ei;
    const int* dst = ei + N_EDGES;
    const int* batch = (const int*)d_in[2];
    const float* ibn_g = (const float*)d_in[3];
    const float* ibn_b = (const float*)d_in[4];
    const float* eps = (const float*)d_in[5];
    const float* fc1w = (const float*)d_in[6];
    const float* fc1b = (const float*)d_in[7];
    const float* bn1g = (const float*)d_in[8];
    const float* bn1b = (const float*)d_in[9];
    const float* fc2w = (const float*)d_in[10];
    const float* fc2b = (const float*)d_in[11];
    const float* bng = (const float*)d_in[12];
    const float* bnb = (const float*)d_in[13];
    const float* att = (const float*)d_in[14];
    const float* pw = (const float*)d_in[15];
    const float* fcAw = (const float*)d_in[16];
    const float* fcAb = (const float*)d_in[17];
    const float* lng = (const float*)d_in[18];
    const float* lnb = (const float*)d_in[19];
    const float* fcBw = (const float*)d_in[20];
    const float* fcBb = (const float*)d_in[21];
    float* out = (float*)d_out;

    const size_t NH = (size_t)N_NODES * HID;
    char* w8 = (char*)d_ws;
    ushort* x0bf = (ushort*)w8;     w8 += NH * 2;
    ushort* hprebf = (ushort*)w8;   w8 += NH * 2;  // gather out / MLP in
    ushort* Hlbf[NL];
    for (int l = 0; l < NL; ++l) { Hlbf[l] = (ushort*)w8; w8 += NH * 2; }
    float* statsPart = (float*)w8;  w8 += (size_t)9 * PSET * 4;
    float* psum = (float*)w8;       w8 += (size_t)N_GRAPHS * HID * 4;
    float* pmax = (float*)w8;       w8 += (size_t)N_GRAPHS * HID * 4;
    int* gstart = (int*)w8;         w8 += N_GRAPHS * 4;
    int* gend = (int*)w8;           w8 += N_GRAPHS * 4;
    int* counts = (int*)w8;         w8 += N_NODES * 4;
    int* offs = (int*)w8;           w8 += N_NODES * 4;
    int* cursor = (int*)w8;         w8 += N_NODES * 4;   // legacy slot (keeps r8 layout)
    int* bsum = (int*)w8;           w8 += 256 * 4;
    int* csr = (int*)w8;            w8 += (size_t)N_EDGES * 4;
    ushort* WtBf = (ushort*)w8;     w8 += (size_t)8 * HID * HID * 2;
    int* bar = (int*)w8;            w8 += 2048 * 4;  // 4 regions x 512 ints
    int* cursorPad = (int*)w8;      w8 += (size_t)N_NODES * SSTR * 4;  // 1 ctr/line
    (void)cursor;

    const int edgeBlocks = (N_EDGES + 255) / 256;  // 2344

    // 1: weights + all zero-init
    setup<<<512, 256, 0, stream>>>(fc1w, fc2w, WtBf, counts, statsPart,
                                   psum, pmax, gstart, gend, bar);
    // 2: input col-stats (grouped partials) + CSR degree count + graph ranges
    stats_count<<<256 + edgeBlocks + 196, 256, 0, stream>>>(x, statsPart, dst, counts,
                                                            batch, gstart, gend);
    // 3: input BN apply (fp32 -> bf16; 16-group stat sum) + scan pass 1
    bn_scan<<<2048, 256, 0, stream>>>(x, x0bf, statsPart, ibn_g, ibn_b, counts, offs,
                                      bsum);
    // 4: scan passes 2+3 -> offs, padded cursor
    scan23<<<196, 256, 0, stream>>>(offs, bsum, cursorPad);
    // 5: CSR fill (value-returning atomics on padded lines)
    csr_fill<<<edgeBlocks, 256, 0, stream>>>(src, dst, cursorPad, csr);

    // Layers: dedicated gather + persistent fused MLP (champion structure).
    // Layer 3 fuses JK attention + pooling into phase C.
    const ushort* xin = x0bf;
    for (int l = 0; l < NL; ++l) {
        float* p1 = statsPart + (size_t)(1 + 2 * l) * PSET;
        float* p2 = statsPart + (size_t)(2 + 2 * l) * PSET;
        gin_gather_bf<<<2048, 256, 0, stream>>>(xin, hprebf, offs, counts, csr, eps, l);
        if (l < 3) {
            fused_mlp<512, false><<<256, 512, 0, stream>>>(
                hprebf, WtBf + (size_t)l * HID * HID,
                WtBf + (size_t)(4 + l) * HID * HID, fc1b + l * HID, fc2b + l * HID,
                bn1g + l * HID, bn1b + l * HID, bng + l * HID, bnb + l * HID,
                p1, p2, Hlbf[l], bar + l * 512,
                nullptr, nullptr, nullptr, nullptr, nullptr, nullptr, nullptr);
        } else {
            fused_mlp<512, true><<<256, 512, 0, stream>>>(
                hprebf, WtBf + (size_t)l * HID * HID,
                WtBf + (size_t)(4 + l) * HID * HID, fc1b + l * HID, fc2b + l * HID,
                bn1g + l * HID, bn1b + l * HID, bng + l * HID, bnb + l * HID,
                p1, p2, Hlbf[l], bar + l * 512,
                Hlbf[0], Hlbf[1], Hlbf[2], att, batch, psum, pmax);
        }
        xin = Hlbf[l];
    }

    finalize_head<<<N_GRAPHS, 128, 0, stream>>>(psum, pmax, gstart, gend, pw, fcAw,
                                                fcAb, lng, lnb, fcBw, fcBb, out);
}